// Round 1
// baseline (278.844 us; speedup 1.0000x reference)
//
#include <hip/hip_runtime.h>

#define NN 50000
#define NE 1000000
#define D  64
#define ED 16
#define BN_EPS 1e-5f

// ---------------- edge stage: ea = edge_attr@W_edge^T + b_edge;
//                  msg = relu(x[src]+ea); agg[dst] += msg -------------------
__global__ __launch_bounds__(256) void edge_kernel(
    const float* __restrict__ x,
    const int*   __restrict__ ei32,     // edge_index, int32 or int64 (detected)
    const float* __restrict__ ea,
    const float* __restrict__ W_edge,
    const float* __restrict__ b_edge,
    float*       __restrict__ agg)
{
    __shared__ float s_ea[64 * ED];
    __shared__ int   s_src[64];
    __shared__ int   s_dst[64];

    const int tid  = threadIdx.x;
    const int lane = tid & 63;
    const int wave = tid >> 6;
    const long long ebase = (long long)blockIdx.x * 64;

    // int64-vs-int32 detection: node ids < 50000, so int64 high words are 0.
    const int hi = ei32[2 * lane + 1];
    const bool is64 = !__any(hi != 0);

    // W_edge row for this lane (output channel) in registers
    float w[ED];
    #pragma unroll
    for (int i = 0; i < ED / 4; ++i) {
        float4 t = reinterpret_cast<const float4*>(W_edge)[lane * (ED / 4) + i];
        w[4*i+0] = t.x; w[4*i+1] = t.y; w[4*i+2] = t.z; w[4*i+3] = t.w;
    }
    const float bo = b_edge[lane];

    // stage 64 edges x 16 attrs (coalesced float4)
    reinterpret_cast<float4*>(s_ea)[tid] =
        reinterpret_cast<const float4*>(ea + ebase * ED)[tid];

    if (tid < 64) {
        long long e = ebase + tid;
        s_src[tid] = is64 ? ei32[2 * e] : ei32[e];
    } else if (tid < 128) {
        long long e = ebase + (tid - 64);
        s_dst[tid - 64] = is64 ? ei32[2 * (NE + e)] : ei32[NE + e];
    }
    __syncthreads();

    #pragma unroll 4
    for (int i = 0; i < 16; ++i) {
        const int el = wave * 16 + i;
        float acc = bo;
        const float* er = s_ea + el * ED;
        #pragma unroll
        for (int k = 0; k < ED; ++k) acc += er[k] * w[k];
        const long long s = s_src[el];
        const long long d = s_dst[el];
        float m = fmaxf(acc + x[s * D + lane], 0.f);
        atomicAdd(&agg[d * D + lane], m);
    }
}

// ---------------- node stage 1: h1 = (x+agg)@W1^T + b1, column stats -------
__global__ __launch_bounds__(256) void node1_kernel(
    const float* __restrict__ x,
    const float* __restrict__ agg,
    const float* __restrict__ W1,
    const float* __restrict__ b1,
    float*       __restrict__ h1,
    float*       __restrict__ colsum,
    float*       __restrict__ colsumsq)
{
    __shared__ float s_h[64 * D];
    const int tid  = threadIdx.x;
    const int o    = tid & 63;
    const int wave = tid >> 6;
    const long long rbase = (long long)blockIdx.x * 64;

    // W1 row o in registers
    float w[D];
    #pragma unroll
    for (int i = 0; i < D / 4; ++i) {
        float4 t = reinterpret_cast<const float4*>(W1)[o * (D / 4) + i];
        w[4*i+0] = t.x; w[4*i+1] = t.y; w[4*i+2] = t.z; w[4*i+3] = t.w;
    }

    // stage h = x + agg tile (64 rows)
    #pragma unroll
    for (int i = 0; i < 4; ++i) {
        const int f4 = tid + 256 * i;              // 0..1023 float4s
        const long long row = rbase + (f4 >> 4);   // 16 float4 per row
        float4 t = make_float4(0.f, 0.f, 0.f, 0.f);
        if (row < NN) {
            float4 a = reinterpret_cast<const float4*>(x)  [row * (D/4) + (f4 & 15)];
            float4 g = reinterpret_cast<const float4*>(agg)[row * (D/4) + (f4 & 15)];
            t.x = a.x + g.x; t.y = a.y + g.y; t.z = a.z + g.z; t.w = a.w + g.w;
        }
        reinterpret_cast<float4*>(s_h)[f4] = t;
    }
    __syncthreads();

    const float bb = b1[o];
    float psum = 0.f, psq = 0.f;
    for (int i = 0; i < 16; ++i) {
        const int r = wave + 4 * i;
        const long long row = rbase + r;
        float acc = bb;
        const float4* sr = reinterpret_cast<const float4*>(s_h + r * D);
        #pragma unroll
        for (int k = 0; k < D / 4; ++k) {
            float4 v = sr[k];
            acc += v.x * w[4*k+0] + v.y * w[4*k+1] + v.z * w[4*k+2] + v.w * w[4*k+3];
        }
        if (row < NN) {
            h1[row * D + o] = acc;
            psum += acc;
            psq  += acc * acc;
        }
    }
    __syncthreads();
    s_h[wave * 64 + o]       = psum;
    s_h[256 + wave * 64 + o] = psq;
    __syncthreads();
    if (tid < 64) {
        float s0 = s_h[tid] + s_h[64 + tid] + s_h[128 + tid] + s_h[192 + tid];
        float q0 = s_h[256 + tid] + s_h[320 + tid] + s_h[384 + tid] + s_h[448 + tid];
        atomicAdd(&colsum[tid], s0);
        atomicAdd(&colsumsq[tid], q0);
    }
}

// ---------------- BN stats fold ----------------
__global__ void bnstats_kernel(
    const float* __restrict__ colsum,
    const float* __restrict__ colsumsq,
    const float* __restrict__ gamma,
    const float* __restrict__ beta,
    float*       __restrict__ scale,
    float*       __restrict__ shift)
{
    const int o = threadIdx.x;
    const float inv_n = 1.f / (float)NN;
    const float mean = colsum[o] * inv_n;
    const float var  = colsumsq[o] * inv_n - mean * mean;
    const float sc   = gamma[o] * rsqrtf(var + BN_EPS);
    scale[o] = sc;
    shift[o] = beta[o] - mean * sc;
}

// ---------------- node stage 2: out = relu(bn(h1))@W2^T + b2 ---------------
__global__ __launch_bounds__(256) void node2_kernel(
    const float* __restrict__ h1,
    const float* __restrict__ scale,
    const float* __restrict__ shift,
    const float* __restrict__ W2,
    const float* __restrict__ b2,
    float*       __restrict__ out)
{
    __shared__ float s_a[64 * D];
    __shared__ float s_sc[D];
    __shared__ float s_sh[D];
    const int tid  = threadIdx.x;
    const int o    = tid & 63;
    const int wave = tid >> 6;
    const long long rbase = (long long)blockIdx.x * 64;

    if (tid < D) { s_sc[tid] = scale[tid]; s_sh[tid] = shift[tid]; }

    float w[D];
    #pragma unroll
    for (int i = 0; i < D / 4; ++i) {
        float4 t = reinterpret_cast<const float4*>(W2)[o * (D / 4) + i];
        w[4*i+0] = t.x; w[4*i+1] = t.y; w[4*i+2] = t.z; w[4*i+3] = t.w;
    }
    __syncthreads();

    #pragma unroll
    for (int i = 0; i < 4; ++i) {
        const int f4 = tid + 256 * i;
        const long long row = rbase + (f4 >> 4);
        float4 t = make_float4(0.f, 0.f, 0.f, 0.f);
        if (row < NN) {
            float4 v = reinterpret_cast<const float4*>(h1)[row * (D/4) + (f4 & 15)];
            const int c = (f4 & 15) * 4;
            t.x = fmaxf(v.x * s_sc[c+0] + s_sh[c+0], 0.f);
            t.y = fmaxf(v.y * s_sc[c+1] + s_sh[c+1], 0.f);
            t.z = fmaxf(v.z * s_sc[c+2] + s_sh[c+2], 0.f);
            t.w = fmaxf(v.w * s_sc[c+3] + s_sh[c+3], 0.f);
        }
        reinterpret_cast<float4*>(s_a)[f4] = t;
    }
    __syncthreads();

    const float bb = b2[o];
    for (int i = 0; i < 16; ++i) {
        const int r = wave + 4 * i;
        const long long row = rbase + r;
        float acc = bb;
        const float4* sr = reinterpret_cast<const float4*>(s_a + r * D);
        #pragma unroll
        for (int k = 0; k < D / 4; ++k) {
            float4 v = sr[k];
            acc += v.x * w[4*k+0] + v.y * w[4*k+1] + v.z * w[4*k+2] + v.w * w[4*k+3];
        }
        if (row < NN) out[row * D + o] = acc;
    }
}

extern "C" void kernel_launch(void* const* d_in, const int* in_sizes, int n_in,
                              void* d_out, int out_size, void* d_ws, size_t ws_size,
                              hipStream_t stream)
{
    const float* x      = (const float*)d_in[0];
    const int*   ei32   = (const int*)  d_in[1];   // int32 or int64 (runtime-detected)
    const float* ea     = (const float*)d_in[2];
    const float* W_edge = (const float*)d_in[3];
    const float* b_edge = (const float*)d_in[4];
    const float* W1     = (const float*)d_in[5];
    const float* b1     = (const float*)d_in[6];
    const float* gamma  = (const float*)d_in[7];
    const float* beta   = (const float*)d_in[8];
    const float* W2     = (const float*)d_in[9];
    const float* b2     = (const float*)d_in[10];
    float* out = (float*)d_out;

    // workspace layout (floats)
    float* agg      = (float*)d_ws;                      // NN*D
    float* colsum   = agg + (size_t)NN * D;              // 64
    float* colsumsq = colsum + 64;                       // 64
    float* h1       = colsumsq + 64;                     // NN*D  (16B-aligned: offset%4==0)
    float* scale    = h1 + (size_t)NN * D;               // 64
    float* shift    = scale + 64;                        // 64

    hipMemsetAsync(agg, 0, ((size_t)NN * D + 128) * sizeof(float), stream);

    edge_kernel<<<NE / 64, 256, 0, stream>>>(x, ei32, ea, W_edge, b_edge, agg);
    node1_kernel<<<(NN + 63) / 64, 256, 0, stream>>>(x, agg, W1, b1, h1, colsum, colsumsq);
    bnstats_kernel<<<1, 64, 0, stream>>>(colsum, colsumsq, gamma, beta, scale, shift);
    node2_kernel<<<(NN + 63) / 64, 256, 0, stream>>>(h1, scale, shift, W2, b2, out);
}